// Round 1
// baseline (1253.168 us; speedup 1.0000x reference)
//
#include <hip/hip_runtime.h>
#include <hip/hip_bf16.h>
#include <cstdint>

typedef __bf16 bf16x8 __attribute__((ext_vector_type(8)));
typedef float floatx4 __attribute__((ext_vector_type(4)));

__device__ __forceinline__ unsigned short f2bf(float f) {
  union { float f; unsigned int u; } v;
  v.f = f;
  unsigned int r = v.u + 0x7FFFu + ((v.u >> 16) & 1u);  // RNE
  return (unsigned short)(r >> 16);
}

// ---------------------------------------------------------------------------
// Kernel 1: gumbel 2:4 mask + masked weight -> bf16
// scores/noise_u/weight all share flat layout [out, g, m] -> group = gid*4.
// ---------------------------------------------------------------------------
__global__ __launch_bounds__(256) void mask_weight_k(
    const float4* __restrict__ w, const float4* __restrict__ s,
    const float4* __restrict__ u, ushort4* __restrict__ wb, int ngroups)
{
  int gid = blockIdx.x * blockDim.x + threadIdx.x;
  if (gid >= ngroups) return;
  float4 sv = s[gid];
  float4 uv = u[gid];
  float4 wv = w[gid];
  const float EPS = 1e-10f;
  float y[4];
  y[0] = sv.x - logf(-logf(uv.x + EPS) + EPS);
  y[1] = sv.y - logf(-logf(uv.y + EPS) + EPS);
  y[2] = sv.z - logf(-logf(uv.z + EPS) + EPS);
  y[3] = sv.w - logf(-logf(uv.w + EPS) + EPS);
  // top-2 with lowest-index tie-break (matches jax.lax.top_k ordering)
  int i1 = 0;
#pragma unroll
  for (int k = 1; k < 4; ++k)
    if (y[k] > y[i1]) i1 = k;
  int i2 = -1;
#pragma unroll
  for (int k = 0; k < 4; ++k) {
    if (k == i1) continue;
    if (i2 < 0 || y[k] > y[i2]) i2 = k;
  }
  ushort4 o;
  o.x = (i1 == 0 || i2 == 0) ? f2bf(wv.x) : (unsigned short)0;
  o.y = (i1 == 1 || i2 == 1) ? f2bf(wv.y) : (unsigned short)0;
  o.z = (i1 == 2 || i2 == 2) ? f2bf(wv.z) : (unsigned short)0;
  o.w = (i1 == 3 || i2 == 3) ? f2bf(wv.w) : (unsigned short)0;
  wb[gid] = o;
}

// ---------------------------------------------------------------------------
// Kernel 2: x fp32 -> bf16
// ---------------------------------------------------------------------------
__global__ __launch_bounds__(256) void cast_x_k(
    const float4* __restrict__ x, ushort4* __restrict__ xb, int n4)
{
  int i = blockIdx.x * blockDim.x + threadIdx.x;
  if (i >= n4) return;
  float4 v = x[i];
  ushort4 o;
  o.x = f2bf(v.x);
  o.y = f2bf(v.y);
  o.z = f2bf(v.z);
  o.w = f2bf(v.w);
  xb[i] = o;
}

// ---------------------------------------------------------------------------
// Kernel 3: bf16 NT GEMM  C[M,N] = A[M,K] * B[N,K]^T + bias  (m97 structure)
// 128x128 tile, BK=32, 256 threads (4 waves, 2x2), 4x4 MFMA 16x16x32 per wave
// ---------------------------------------------------------------------------
__global__ __launch_bounds__(256) void gemm_bt(
    const __bf16* __restrict__ A, const __bf16* __restrict__ B,
    const float* __restrict__ bias, float* __restrict__ C,
    int M, int N, int K)
{
  constexpr int BM = 128, BN = 128, BK = 32;
  __shared__ __bf16 sA[BM * BK];
  __shared__ __bf16 sB[BN * BK];

  const int tid  = threadIdx.x;
  const int lane = tid & 63;
  const int wave = tid >> 6;
  const int bm = blockIdx.y * BM;
  const int bn = blockIdx.x * BN;
  const int wm = (wave >> 1) * 64;  // 0 or 64
  const int wn = (wave & 1) * 64;

  // Staging: tile = 128 rows x 64 B = 8192 B = 512 x 16 B chunks; 2 per thread.
  // Chunk byte offset o = tid*16 (+4096). Row = o>>6, col-byte = o&63.
  // LDS dest is contiguous at byte tid*16 (+4096) -> wave-uniform base + lane*16. OK.
  const int o0 = tid * 16;
  const int r0 = o0 >> 6;
  const int cb = o0 & 63;
  const int r1 = (o0 + 4096) >> 6;  // same col-byte

  const int qm = lane >> 4;   // quad 0..3
  const int rm = lane & 15;

  floatx4 acc[4][4];
#pragma unroll
  for (int i = 0; i < 4; ++i)
#pragma unroll
    for (int j = 0; j < 4; ++j)
      acc[i][j] = (floatx4){0.f, 0.f, 0.f, 0.f};

  const size_t ldab = (size_t)K * 2;  // row stride in bytes
  const char* gA = (const char*)(A + (size_t)bm * K);
  const char* gB = (const char*)(B + (size_t)bn * K);
  char* lA = (char*)&sA[0];
  char* lB = (char*)&sB[0];

  for (int k0 = 0; k0 < K; k0 += BK) {
    const size_t kb = (size_t)k0 * 2;
    __builtin_amdgcn_global_load_lds(
        (const __attribute__((address_space(1))) void*)(gA + (size_t)r0 * ldab + kb + cb),
        (__attribute__((address_space(3))) void*)(lA + o0), 16, 0, 0);
    __builtin_amdgcn_global_load_lds(
        (const __attribute__((address_space(1))) void*)(gA + (size_t)r1 * ldab + kb + cb),
        (__attribute__((address_space(3))) void*)(lA + o0 + 4096), 16, 0, 0);
    __builtin_amdgcn_global_load_lds(
        (const __attribute__((address_space(1))) void*)(gB + (size_t)r0 * ldab + kb + cb),
        (__attribute__((address_space(3))) void*)(lB + o0), 16, 0, 0);
    __builtin_amdgcn_global_load_lds(
        (const __attribute__((address_space(1))) void*)(gB + (size_t)r1 * ldab + kb + cb),
        (__attribute__((address_space(3))) void*)(lB + o0 + 4096), 16, 0, 0);
    __syncthreads();

    bf16x8 af[4], bf[4];
#pragma unroll
    for (int i = 0; i < 4; ++i)
      af[i] = *(const bf16x8*)(sA + (wm + i * 16 + rm) * BK + qm * 8);
#pragma unroll
    for (int j = 0; j < 4; ++j)
      bf[j] = *(const bf16x8*)(sB + (wn + j * 16 + rm) * BK + qm * 8);
#pragma unroll
    for (int i = 0; i < 4; ++i)
#pragma unroll
      for (int j = 0; j < 4; ++j)
        acc[i][j] = __builtin_amdgcn_mfma_f32_16x16x32_bf16(af[i], bf[j], acc[i][j], 0, 0, 0);
    __syncthreads();
  }

  // Epilogue: C/D layout row = quad*4 + r (A's m), col = lane&15 (B's n)
#pragma unroll
  for (int j = 0; j < 4; ++j) {
    const int n = bn + wn + j * 16 + rm;
    const float bv = bias[n];
#pragma unroll
    for (int i = 0; i < 4; ++i) {
      const int mr = bm + wm + i * 16 + qm * 4;
      float* cp = C + (size_t)mr * N + n;
#pragma unroll
      for (int r = 0; r < 4; ++r)
        cp[(size_t)r * N] = acc[i][j][r] + bv;
    }
  }
}

// ---------------------------------------------------------------------------
extern "C" void kernel_launch(void* const* d_in, const int* in_sizes, int n_in,
                              void* d_out, int out_size, void* d_ws, size_t ws_size,
                              hipStream_t stream)
{
  const float* x      = (const float*)d_in[0];
  const float* weight = (const float*)d_in[1];
  const float* bias   = (const float*)d_in[2];
  const float* scores = (const float*)d_in[3];
  const float* noise  = (const float*)d_in[4];
  float* out = (float*)d_out;

  const int N = in_sizes[2];            // 4096 (D_OUT)
  const int K = in_sizes[1] / N;        // 4096 (D_IN)
  const int M = in_sizes[0] / K;        // 16384 (B*S)

  __bf16* xb = (__bf16*)d_ws;
  __bf16* wb = (__bf16*)((char*)d_ws + (size_t)M * K * sizeof(__bf16));

  const int ngroups = (N * K) / 4;      // 4,194,304
  mask_weight_k<<<dim3((ngroups + 255) / 256), dim3(256), 0, stream>>>(
      (const float4*)weight, (const float4*)scores, (const float4*)noise,
      (ushort4*)wb, ngroups);

  const int n4 = (int)(((size_t)M * K) / 4);  // 16,777,216
  cast_x_k<<<dim3((n4 + 255) / 256), dim3(256), 0, stream>>>(
      (const float4*)x, (ushort4*)xb, n4);

  dim3 grid(N / 128, M / 128);
  gemm_bt<<<grid, dim3(256), 0, stream>>>(xb, wb, bias, out, M, N, K);
}

// Round 2
// 1234.332 us; speedup vs baseline: 1.0153x; 1.0153x over previous
//
#include <hip/hip_runtime.h>
#include <hip/hip_bf16.h>
#include <cstdint>

typedef __bf16 bf16x8 __attribute__((ext_vector_type(8)));
typedef float floatx4 __attribute__((ext_vector_type(4)));

__device__ __forceinline__ unsigned short f2bf(float f) {
  union { float f; unsigned int u; } v;
  v.f = f;
  unsigned int r = v.u + 0x7FFFu + ((v.u >> 16) & 1u);  // RNE
  return (unsigned short)(r >> 16);
}

// ---------------------------------------------------------------------------
// Kernel 1: gumbel 2:4 mask + masked weight -> bf16
// ---------------------------------------------------------------------------
__global__ __launch_bounds__(256) void mask_weight_k(
    const float4* __restrict__ w, const float4* __restrict__ s,
    const float4* __restrict__ u, ushort4* __restrict__ wb, int ngroups)
{
  int gid = blockIdx.x * blockDim.x + threadIdx.x;
  if (gid >= ngroups) return;
  float4 sv = s[gid];
  float4 uv = u[gid];
  float4 wv = w[gid];
  const float EPS = 1e-10f;
  float y[4];
  y[0] = sv.x - logf(-logf(uv.x + EPS) + EPS);
  y[1] = sv.y - logf(-logf(uv.y + EPS) + EPS);
  y[2] = sv.z - logf(-logf(uv.z + EPS) + EPS);
  y[3] = sv.w - logf(-logf(uv.w + EPS) + EPS);
  // top-2 with lowest-index tie-break (matches jax.lax.top_k ordering)
  int i1 = 0;
#pragma unroll
  for (int k = 1; k < 4; ++k)
    if (y[k] > y[i1]) i1 = k;
  int i2 = -1;
#pragma unroll
  for (int k = 0; k < 4; ++k) {
    if (k == i1) continue;
    if (i2 < 0 || y[k] > y[i2]) i2 = k;
  }
  ushort4 o;
  o.x = (i1 == 0 || i2 == 0) ? f2bf(wv.x) : (unsigned short)0;
  o.y = (i1 == 1 || i2 == 1) ? f2bf(wv.y) : (unsigned short)0;
  o.z = (i1 == 2 || i2 == 2) ? f2bf(wv.z) : (unsigned short)0;
  o.w = (i1 == 3 || i2 == 3) ? f2bf(wv.w) : (unsigned short)0;
  wb[gid] = o;
}

// ---------------------------------------------------------------------------
// Kernel 2: x fp32 -> bf16
// ---------------------------------------------------------------------------
__global__ __launch_bounds__(256) void cast_x_k(
    const float4* __restrict__ x, ushort4* __restrict__ xb, int n4)
{
  int i = blockIdx.x * blockDim.x + threadIdx.x;
  if (i >= n4) return;
  float4 v = x[i];
  ushort4 o;
  o.x = f2bf(v.x);
  o.y = f2bf(v.y);
  o.z = f2bf(v.z);
  o.w = f2bf(v.w);
  xb[i] = o;
}

// ---------------------------------------------------------------------------
// Kernel 3: bf16 NT GEMM  C[M,N] = A[M,K] * B[N,K]^T + bias
// 128x128 tile, BK=32, 256 threads (4 waves, 2x2), 4x4 MFMA 16x16x32 per wave.
// LDS 16B-chunk XOR swizzle (c' = c ^ ((row>>1)&3)) applied on the GLOBAL
// fetch side (global_load_lds dest is lane-contiguous); readers un-swizzle.
// Spreads the 16-lane read phases across all 8 bank groups -> conflict-free.
// ---------------------------------------------------------------------------
__global__ __launch_bounds__(256) void gemm_bt(
    const __bf16* __restrict__ A, const __bf16* __restrict__ B,
    const float* __restrict__ bias, float* __restrict__ C,
    int M, int N, int K)
{
  constexpr int BM = 128, BN = 128, BK = 32;
  __shared__ __bf16 sA[BM * BK];
  __shared__ __bf16 sB[BN * BK];

  const int tid  = threadIdx.x;
  const int lane = tid & 63;
  const int wave = tid >> 6;
  const int bm = blockIdx.y * BM;
  const int bn = blockIdx.x * BN;
  const int wm = (wave >> 1) * 64;  // 0 or 64
  const int wn = (wave & 1) * 64;

  // Staging: tile = 128 rows x 64 B = 8192 B = 512 x 16B chunks; 2 per thread.
  // LDS slot byte o = tid*16 (+4096): row = o>>6, slot chunk = (o>>4)&3.
  // Global chunk fetched into that slot: c ^ ((row>>1)&3)  (same for both
  // chunks: r1 = r0+64 keeps (row>>1)&3 invariant).
  const int o0 = tid * 16;
  const int r0 = o0 >> 6;
  const int c0 = (o0 >> 4) & 3;
  const int cbg = (c0 ^ ((r0 >> 1) & 3)) * 16;  // swizzled global col-byte
  const int r1 = r0 + 64;

  const int qm = lane >> 4;   // quad 0..3
  const int rm = lane & 15;
  const int swz = (rm >> 1) & 3;  // reader swizzle term (wm, i*16 vanish)

  floatx4 acc[4][4];
#pragma unroll
  for (int i = 0; i < 4; ++i)
#pragma unroll
    for (int j = 0; j < 4; ++j)
      acc[i][j] = (floatx4){0.f, 0.f, 0.f, 0.f};

  const size_t ldab = (size_t)K * 2;  // row stride in bytes
  const char* gA = (const char*)(A + (size_t)bm * K);
  const char* gB = (const char*)(B + (size_t)bn * K);
  char* lA = (char*)&sA[0];
  char* lB = (char*)&sB[0];

  const int chunkA = (qm ^ swz) * 16;  // byte offset of wanted chunk in LDS row

  for (int k0 = 0; k0 < K; k0 += BK) {
    const size_t kb = (size_t)k0 * 2;
    __builtin_amdgcn_global_load_lds(
        (const __attribute__((address_space(1))) void*)(gA + (size_t)r0 * ldab + kb + cbg),
        (__attribute__((address_space(3))) void*)(lA + o0), 16, 0, 0);
    __builtin_amdgcn_global_load_lds(
        (const __attribute__((address_space(1))) void*)(gA + (size_t)r1 * ldab + kb + cbg),
        (__attribute__((address_space(3))) void*)(lA + o0 + 4096), 16, 0, 0);
    __builtin_amdgcn_global_load_lds(
        (const __attribute__((address_space(1))) void*)(gB + (size_t)r0 * ldab + kb + cbg),
        (__attribute__((address_space(3))) void*)(lB + o0), 16, 0, 0);
    __builtin_amdgcn_global_load_lds(
        (const __attribute__((address_space(1))) void*)(gB + (size_t)r1 * ldab + kb + cbg),
        (__attribute__((address_space(3))) void*)(lB + o0 + 4096), 16, 0, 0);
    __syncthreads();

    bf16x8 af[4], bf[4];
#pragma unroll
    for (int i = 0; i < 4; ++i)
      af[i] = *(const bf16x8*)(lA + (wm + i * 16 + rm) * 64 + chunkA);
#pragma unroll
    for (int j = 0; j < 4; ++j)
      bf[j] = *(const bf16x8*)(lB + (wn + j * 16 + rm) * 64 + chunkA);
#pragma unroll
    for (int i = 0; i < 4; ++i)
#pragma unroll
      for (int j = 0; j < 4; ++j)
        acc[i][j] = __builtin_amdgcn_mfma_f32_16x16x32_bf16(af[i], bf[j], acc[i][j], 0, 0, 0);
    __syncthreads();
  }

  // Epilogue: C/D layout row = quad*4 + r (A's m), col = lane&15 (B's n)
#pragma unroll
  for (int j = 0; j < 4; ++j) {
    const int n = bn + wn + j * 16 + rm;
    const float bv = bias[n];
#pragma unroll
    for (int i = 0; i < 4; ++i) {
      const int mr = bm + wm + i * 16 + qm * 4;
      float* cp = C + (size_t)mr * N + n;
#pragma unroll
      for (int r = 0; r < 4; ++r)
        cp[(size_t)r * N] = acc[i][j][r] + bv;
    }
  }
}

// ---------------------------------------------------------------------------
extern "C" void kernel_launch(void* const* d_in, const int* in_sizes, int n_in,
                              void* d_out, int out_size, void* d_ws, size_t ws_size,
                              hipStream_t stream)
{
  const float* x      = (const float*)d_in[0];
  const float* weight = (const float*)d_in[1];
  const float* bias   = (const float*)d_in[2];
  const float* scores = (const float*)d_in[3];
  const float* noise  = (const float*)d_in[4];
  float* out = (float*)d_out;

  const int N = in_sizes[2];            // 4096 (D_OUT)
  const int K = in_sizes[1] / N;        // 4096 (D_IN)
  const int M = in_sizes[0] / K;        // 16384 (B*S)

  __bf16* xb = (__bf16*)d_ws;
  __bf16* wb = (__bf16*)((char*)d_ws + (size_t)M * K * sizeof(__bf16));

  const int ngroups = (N * K) / 4;      // 4,194,304
  mask_weight_k<<<dim3((ngroups + 255) / 256), dim3(256), 0, stream>>>(
      (const float4*)weight, (const float4*)scores, (const float4*)noise,
      (ushort4*)wb, ngroups);

  const int n4 = (int)(((size_t)M * K) / 4);  // 16,777,216
  cast_x_k<<<dim3((n4 + 255) / 256), dim3(256), 0, stream>>>(
      (const float4*)x, (ushort4*)xb, n4);

  dim3 grid(N / 128, M / 128);
  gemm_bt<<<grid, dim3(256), 0, stream>>>(xb, wb, bias, out, M, N, K);
}